// Round 15
// baseline (116.119 us; speedup 1.0000x reference)
//
#include <hip/hip_runtime.h>
#include <math.h>

// NaiveDFTQNN: 25-wire state vector, DIM = 2^25.
// out = (cos(theta[0]/2)/||f||) * (tensor product of 12 Givens rotations) * f
// Pair j (j=0..11) acts on little-endian element bits (2j+1, 2j), angle theta[11-j]/2:
//   v=01: n01 = c*a01 - s*a10 ; v=10: n10 = s*a01 + c*a10 ; v=00,11 untouched.
// Bit 24 (wire 0) is a spectator (RX folds into the scalar).
//
// Cache-steering ledger (A/B r6..r13): `in` NT-load; intermediate regular store
// + regular load; final NT-store. NT anywhere on the intermediate loses.
// r15: j7 moved into p1 via block-parity tile pairing (odd blocks hold the
// (b15,b14)=(01)/(10) tile pair and rotate across register tiles; even blocks
// hold (00)/(11), j7 = identity). High then covers only j8..j11 (el 16..23),
// H = 8 bits -> payload el 2..6 = 512 B granules (granule size is the proven
// knob: 128->256 B gave +4 us in r14). High needs no lane shuffles at all.

typedef float f32x4 __attribute__((ext_vector_type(4)));

static __device__ __forceinline__ float4 nt_load4(const float* p) {
    f32x4 v = __builtin_nontemporal_load((const f32x4*)p);
    return *(float4*)&v;
}
static __device__ __forceinline__ void nt_store4(float* p, float4 v) {
    __builtin_nontemporal_store(*(f32x4*)&v, (f32x4*)p);
}

// Barrier that drains ONLY lgkmcnt (LDS) — global loads/stores stay in flight.
static __device__ __forceinline__ void bar_lgkm() {
    asm volatile("s_waitcnt lgkmcnt(0)\n\ts_barrier" ::: "memory");
}

static __device__ __forceinline__ void rot4(float4& a, float4& b, float c, float s) {
    float4 na, nb;
    na.x = c*a.x - s*b.x;  nb.x = s*a.x + c*b.x;
    na.y = c*a.y - s*b.y;  nb.y = s*a.y + c*b.y;
    na.z = c*a.z - s*b.z;  nb.z = s*a.z + c*b.z;
    na.w = c*a.w - s*b.w;  nb.w = s*a.w + c*b.w;
    a = na; b = nb;
}

static __device__ __forceinline__ float4 shflx4(float4 v, int m) {
    float4 r;
    r.x = __shfl_xor(v.x, m, 64);
    r.y = __shfl_xor(v.y, m, 64);
    r.z = __shfl_xor(v.z, m, 64);
    r.w = __shfl_xor(v.w, m, 64);
    return r;
}

template <int NR>
static __device__ __forceinline__ void rotshfl(float4* f, int sh, float c, float s, int lane) {
    const int pv = (lane >> sh) & 3;
    const bool act = (pv == 1) || (pv == 2);
    const float cl = act ? c : 1.0f;
    const float sl = act ? ((pv == 1) ? -s : s) : 0.0f;
    const int m = 3 << sh;
#pragma unroll
    for (int k = 0; k < NR; ++k) {
        float4 p = shflx4(f[k], m);
        float4 n;
        n.x = fmaf(sl, p.x, cl * f[k].x);
        n.y = fmaf(sl, p.y, cl * f[k].y);
        n.z = fmaf(sl, p.z, cl * f[k].z);
        n.w = fmaf(sl, p.w, cl * f[k].w);
        f[k] = n;
    }
}

// fp32 pairwise-tree sum of squares over 16 float4 (64 values).
static __device__ __forceinline__ float sumsq16(const float4* f) {
    float q[16];
#pragma unroll
    for (int k = 0; k < 16; ++k)
        q[k] = fmaf(f[k].x, f[k].x,
               fmaf(f[k].y, f[k].y,
               fmaf(f[k].z, f[k].z, f[k].w * f[k].w)));
#pragma unroll
    for (int st = 1; st < 16; st <<= 1)
#pragma unroll
        for (int i = 0; i < 16; i += (st << 1))
            q[i] += q[i + st];
    return q[0];
}

// ---------------- qnn_p1: pairs j0..j7, in -> out, + partials ----------------------
// Tile = contiguous 4096 quads (slot s bits 0..11 = el bits 2..13); 2 tiles/block.
// Block pairing for j7 (el bits 15,14 = quad bits 13,12): h = bid>>1 (el 16..24),
// p = bid&1. p=0: tiles (b15,b14)=(00),(11) — j7 identity. p=1: tiles (01),(10)
// — j7 = rot4(f[k], g[k]) cross-register-tile (f=01, g=10).
// In-tile: j0 components; j1/j2/j3 lane shfl (s 1,0/3,2/5,4); j4 = k(1,0);
// j5 = k(3,2); LDS exchange to s' = m<<8 | w2<<6 | lane: j6 = m(3,2).
// All 32 loads upfront (MLP), 64 KB LDS, lgkm-only barriers.
__global__ __launch_bounds__(256, 2) void qnn_p1(const float* __restrict__ in,
                                                 const float* __restrict__ theta,
                                                 float* __restrict__ out,
                                                 double* __restrict__ partials) {
    __shared__ __align__(16) float4 lds[4096];   // 64 KB
    __shared__ double red[4];
    const int t = threadIdx.x, lane = t & 63, w2 = t >> 6;
    const int bid = blockIdx.x;
    const int h = bid >> 1, p = bid & 1;
    const long gA = ((long)h << 14) | (p ? (1L << 12) : 0);           // (b15,b14): 00 or 01
    const long gB = ((long)h << 14) | (p ? (2L << 12) : (3L << 12));  // 10 or 11

    float c0,s0,c1,s1,c2,s2,c3,s3,c4,s4,c5,s5,c6,s6,c7,s7;
    { float th;
      th=0.5f*theta[11]; c0=cosf(th); s0=sinf(th);
      th=0.5f*theta[10]; c1=cosf(th); s1=sinf(th);
      th=0.5f*theta[9];  c2=cosf(th); s2=sinf(th);
      th=0.5f*theta[8];  c3=cosf(th); s3=sinf(th);
      th=0.5f*theta[7];  c4=cosf(th); s4=sinf(th);
      th=0.5f*theta[6];  c5=cosf(th); s5=sinf(th);
      th=0.5f*theta[5];  c6=cosf(th); s6=sinf(th);
      th=0.5f*theta[4];  c7=cosf(th); s7=sinf(th); }

    float4 f[16], g[16];
    // ---- issue ALL 32 loads upfront ----
#pragma unroll
    for (int k = 0; k < 16; ++k)
        f[k] = nt_load4(in + ((gA + ((w2 << 10) | (k << 6) | lane)) << 2));
#pragma unroll
    for (int k = 0; k < 16; ++k)
        g[k] = nt_load4(in + ((gB + ((w2 << 10) | (k << 6) | lane)) << 2));

    const float sA = sumsq16(f);
    const float sB = sumsq16(g);

    // ---- j7 (cross-register-tile; block-uniform branch) ----
    if (p) {
#pragma unroll
        for (int k = 0; k < 16; ++k) rot4(f[k], g[k], c7, s7);
    }

    // ---- tile A: register rotations j0..j5 ----
#pragma unroll
    for (int k = 0; k < 16; ++k) {
        float ny = c0*f[k].y - s0*f[k].z;
        float nz = s0*f[k].y + c0*f[k].z;
        f[k].y = ny; f[k].z = nz;
    }
    rotshfl<16>(f, 0, c1, s1, lane);
    rotshfl<16>(f, 2, c2, s2, lane);
    rotshfl<16>(f, 4, c3, s3, lane);
#pragma unroll
    for (int hi = 0; hi < 16; hi += 4) rot4(f[hi+1], f[hi+2], c4, s4);
#pragma unroll
    for (int lo = 0; lo < 4; ++lo)     rot4(f[4+lo], f[8+lo], c5, s5);

#pragma unroll
    for (int k = 0; k < 16; ++k) lds[(w2 << 10) | (k << 6) | lane] = f[k];
    bar_lgkm();
#pragma unroll
    for (int m = 0; m < 16; ++m) f[m] = lds[(m << 8) | (w2 << 6) | lane];
#pragma unroll
    for (int lo = 0; lo < 4; ++lo) rot4(f[4+lo], f[8+lo], c6, s6);
#pragma unroll
    for (int m = 0; m < 16; ++m)
        *(float4*)(out + ((gA + ((m << 8) | (w2 << 6) | lane)) << 2)) = f[m];

    // ---- tile B: register rotations j0..j5 ----
#pragma unroll
    for (int k = 0; k < 16; ++k) {
        float ny = c0*g[k].y - s0*g[k].z;
        float nz = s0*g[k].y + c0*g[k].z;
        g[k].y = ny; g[k].z = nz;
    }
    rotshfl<16>(g, 0, c1, s1, lane);
    rotshfl<16>(g, 2, c2, s2, lane);
    rotshfl<16>(g, 4, c3, s3, lane);
#pragma unroll
    for (int hi = 0; hi < 16; hi += 4) rot4(g[hi+1], g[hi+2], c4, s4);
#pragma unroll
    for (int lo = 0; lo < 4; ++lo)     rot4(g[4+lo], g[8+lo], c5, s5);

    bar_lgkm();   // all waves done reading A's LDS image
#pragma unroll
    for (int k = 0; k < 16; ++k) lds[(w2 << 10) | (k << 6) | lane] = g[k];
    bar_lgkm();
#pragma unroll
    for (int m = 0; m < 16; ++m) g[m] = lds[(m << 8) | (w2 << 6) | lane];
#pragma unroll
    for (int lo = 0; lo < 4; ++lo) rot4(g[4+lo], g[8+lo], c6, s6);
#pragma unroll
    for (int m = 0; m < 16; ++m)
        *(float4*)(out + ((gB + ((m << 8) | (w2 << 6) | lane)) << 2)) = g[m];

    // ---- deterministic sumsq partial (f64 cross-lane only) ----
    double acc = (double)sA + (double)sB;
#pragma unroll
    for (int off = 32; off > 0; off >>= 1) acc += __shfl_down(acc, off, 64);
    if (lane == 0) red[w2] = acc;
    bar_lgkm();
    if (t == 0)
        partials[bid] = red[0] + red[1] + red[2] + red[3];
}

// ---------------- Norm: 1024 partials -> scale = cos(theta[0]/2)/sqrt(sum) ---------
__global__ void qnn_norm(const double* __restrict__ partials,
                         const float* __restrict__ theta,
                         double* __restrict__ scale) {
    __shared__ double w[4];
    const int t = threadIdx.x;
    double acc = 0.0;
    for (int i = t; i < 1024; i += 256) acc += partials[i];
#pragma unroll
    for (int off = 32; off > 0; off >>= 1) acc += __shfl_down(acc, off, 64);
    if ((t & 63) == 0) w[t >> 6] = acc;
    __syncthreads();
    if (t == 0) {
        double tot = w[0] + w[1] + w[2] + w[3];
        *scale = (double)cosf(0.5f * theta[0]) / sqrt(tot);
    }
}

// ---------------- qnn_high: pairs j8..j11 (el bits 16..23) + scale, in place -------
// Tile slot s (13 bits) = H<<5 | pq; H = el bits 16..23 (s bits 5..12),
// pq = el bits 2..6 (32 quads = 512 B contiguous granule).
// Global quad = b24<<22 | H<<14 | f1514<<12 | mid<<5 | pq.
// Grid 512: bid = f1514<<7 | mid; tiles A/B = b24 0/1 (2 tiles/block, 32
// upfront loads -> MLP depth preserved per r10 lesson).
// Load layout s = k<<9 | t: j10 = s(10,9) = k(1,0) -> rot4(f[4q+1],f[4q+2]);
// j11 = s(12,11) = k(3,2) -> rot4(f[4+lo],f[8+lo]). No lane shuffles needed.
// LDS exchange to s' = (t>>5)<<9 | m<<5 | (t&31): j8 = m(1,0), j9 = m(3,2).
// Regular loads (IC-resident intermediate), NT final stores, 3 lgkm barriers.
__global__ __launch_bounds__(512, 2) void qnn_high(float* __restrict__ buf,
                                                   const float* __restrict__ theta,
                                                   const double* __restrict__ scale) {
    __shared__ __align__(16) float4 lds[8192];   // 128 KB
    const int t = threadIdx.x;
    const int bid = blockIdx.x;
    const int f1514 = bid >> 7, mid = bid & 127;
    const long gqA = ((long)f1514 << 12) | ((long)mid << 5);   // b24 = 0
    const long gqB = gqA | (1L << 22);                         // b24 = 1

    float c8,s8,c9,s9,c10,s10,c11,s11;
    { float th;
      th=0.5f*theta[3]; c8 =cosf(th); s8 =sinf(th);
      th=0.5f*theta[2]; c9 =cosf(th); s9 =sinf(th);
      th=0.5f*theta[1]; c10=cosf(th); s10=sinf(th);
      th=0.5f*theta[0]; c11=cosf(th); s11=sinf(th); }
    const float sc = (float)(*scale);

    const int rb = ((t >> 5) << 9) | (t & 31);   // LDS read base (s bits 9..12, 0..4)

    float4 f[16], g[16];
    // ---- issue ALL 32 loads (regular; 512 B granules) ----
#pragma unroll
    for (int k = 0; k < 16; ++k) {
        const int s_ = (k << 9) | t;
        f[k] = *(const float4*)(buf + ((gqA | ((long)(s_ >> 5) << 14) | (s_ & 31)) << 2));
    }
#pragma unroll
    for (int k = 0; k < 16; ++k) {
        const int s_ = (k << 9) | t;
        g[k] = *(const float4*)(buf + ((gqB | ((long)(s_ >> 5) << 14) | (s_ & 31)) << 2));
    }

    // ---- register rotations: j10 = k(1,0), j11 = k(3,2) ----
#pragma unroll
    for (int q = 0; q < 16; q += 4) {
        rot4(f[q+1], f[q+2], c10, s10);
        rot4(g[q+1], g[q+2], c10, s10);
    }
#pragma unroll
    for (int lo = 0; lo < 4; ++lo) {
        rot4(f[4+lo], f[8+lo], c11, s11);
        rot4(g[4+lo], g[8+lo], c11, s11);
    }

    // ---- tile A: LDS trip for j8/j9, scale, NT store ----
#pragma unroll
    for (int k = 0; k < 16; ++k) lds[(k << 9) | t] = f[k];
    bar_lgkm();
#pragma unroll
    for (int m = 0; m < 16; ++m) f[m] = lds[rb | (m << 5)];
#pragma unroll
    for (int q = 0; q < 16; q += 4) rot4(f[q+1], f[q+2], c8, s8);   // j8 = m(1,0)
#pragma unroll
    for (int lo = 0; lo < 4; ++lo)  rot4(f[4+lo], f[8+lo], c9, s9); // j9 = m(3,2)
#pragma unroll
    for (int m = 0; m < 16; ++m) {
        const int s_ = rb | (m << 5);
        float4 v = f[m];
        v.x *= sc; v.y *= sc; v.z *= sc; v.w *= sc;
        nt_store4(buf + ((gqA | ((long)(s_ >> 5) << 14) | (s_ & 31)) << 2), v);
    }
    bar_lgkm();   // all waves done reading A's LDS image

    // ---- tile B ----
#pragma unroll
    for (int k = 0; k < 16; ++k) lds[(k << 9) | t] = g[k];
    bar_lgkm();
#pragma unroll
    for (int m = 0; m < 16; ++m) g[m] = lds[rb | (m << 5)];
#pragma unroll
    for (int q = 0; q < 16; q += 4) rot4(g[q+1], g[q+2], c8, s8);
#pragma unroll
    for (int lo = 0; lo < 4; ++lo)  rot4(g[4+lo], g[8+lo], c9, s9);
#pragma unroll
    for (int m = 0; m < 16; ++m) {
        const int s_ = rb | (m << 5);
        float4 v = g[m];
        v.x *= sc; v.y *= sc; v.z *= sc; v.w *= sc;
        nt_store4(buf + ((gqB | ((long)(s_ >> 5) << 14) | (s_ & 31)) << 2), v);
    }
}

extern "C" void kernel_launch(void* const* d_in, const int* in_sizes, int n_in,
                              void* d_out, int out_size, void* d_ws, size_t ws_size,
                              hipStream_t stream) {
    const float* in = (const float*)d_in[0];      // feature, 2^25 f32
    const float* theta = (const float*)d_in[1];   // 13 f32
    float* out = (float*)d_out;                   // 2^25 f32
    double* part = (double*)d_ws;                 // 1024 partials + 1 scale
    double* scale = part + 1024;

    qnn_p1<<<1024, 256, 0, stream>>>(in, theta, out, part);
    qnn_norm<<<1, 256, 0, stream>>>(part, theta, scale);
    qnn_high<<<512, 512, 0, stream>>>(out, theta, scale);
}

// Round 16
// 95.261 us; speedup vs baseline: 1.2190x; 1.2190x over previous
//
#include <hip/hip_runtime.h>
#include <math.h>

// NaiveDFTQNN: 25-wire state vector, DIM = 2^25.
// out = (cos(theta[0]/2)/||f||) * (tensor product of 12 Givens rotations) * f
// Pair j (j=0..11) acts on little-endian element bits (2j+1, 2j), angle theta[11-j]/2:
//   v=01: n01 = c*a01 - s*a10 ; v=10: n10 = s*a01 + c*a10 ; v=00,11 untouched.
// Bit 24 (wire 0) is a spectator (RX folds into the scalar).
//
// Ledger: `in` NT-load; intermediate regular store + regular load; final NT-store.
// r15 lesson: p1's 2-tile overlap must not couple f<->g before A's store phase
// (j7-in-p1 cost +40 us). Cross-tile rotations are fine in HIGH (r14 j11 proof).
// r16: high granule 256 -> 512 B. Payload el 2..6; H = el 14..21 in-slot;
// j11 (el 23,22) via parity tile-pairing (odd blocks rotate (01)x(10), even
// blocks hold (00),(11) = identity). j9/j10 in load-k regs, j7/j8 in read-m
// regs -> high has zero lane shuffles.

typedef float f32x4 __attribute__((ext_vector_type(4)));

static __device__ __forceinline__ float4 nt_load4(const float* p) {
    f32x4 v = __builtin_nontemporal_load((const f32x4*)p);
    return *(float4*)&v;
}
static __device__ __forceinline__ void nt_store4(float* p, float4 v) {
    __builtin_nontemporal_store(*(f32x4*)&v, (f32x4*)p);
}

// Barrier that drains ONLY lgkmcnt (LDS) — global loads/stores stay in flight.
static __device__ __forceinline__ void bar_lgkm() {
    asm volatile("s_waitcnt lgkmcnt(0)\n\ts_barrier" ::: "memory");
}

static __device__ __forceinline__ void rot4(float4& a, float4& b, float c, float s) {
    float4 na, nb;
    na.x = c*a.x - s*b.x;  nb.x = s*a.x + c*b.x;
    na.y = c*a.y - s*b.y;  nb.y = s*a.y + c*b.y;
    na.z = c*a.z - s*b.z;  nb.z = s*a.z + c*b.z;
    na.w = c*a.w - s*b.w;  nb.w = s*a.w + c*b.w;
    a = na; b = nb;
}

static __device__ __forceinline__ float4 shflx4(float4 v, int m) {
    float4 r;
    r.x = __shfl_xor(v.x, m, 64);
    r.y = __shfl_xor(v.y, m, 64);
    r.z = __shfl_xor(v.z, m, 64);
    r.w = __shfl_xor(v.w, m, 64);
    return r;
}

template <int NR>
static __device__ __forceinline__ void rotshfl(float4* f, int sh, float c, float s, int lane) {
    const int pv = (lane >> sh) & 3;
    const bool act = (pv == 1) || (pv == 2);
    const float cl = act ? c : 1.0f;
    const float sl = act ? ((pv == 1) ? -s : s) : 0.0f;
    const int m = 3 << sh;
#pragma unroll
    for (int k = 0; k < NR; ++k) {
        float4 p = shflx4(f[k], m);
        float4 n;
        n.x = fmaf(sl, p.x, cl * f[k].x);
        n.y = fmaf(sl, p.y, cl * f[k].y);
        n.z = fmaf(sl, p.z, cl * f[k].z);
        n.w = fmaf(sl, p.w, cl * f[k].w);
        f[k] = n;
    }
}

// fp32 pairwise-tree sum of squares over 16 float4 (64 values).
static __device__ __forceinline__ float sumsq16(const float4* f) {
    float q[16];
#pragma unroll
    for (int k = 0; k < 16; ++k)
        q[k] = fmaf(f[k].x, f[k].x,
               fmaf(f[k].y, f[k].y,
               fmaf(f[k].z, f[k].z, f[k].w * f[k].w)));
#pragma unroll
    for (int st = 1; st < 16; st <<= 1)
#pragma unroll
        for (int i = 0; i < 16; i += (st << 1))
            q[i] += q[i + st];
    return q[0];
}

// ---------------- qnn_p1: pairs j0..j6 (el bits 0..13), in -> out, + partials ------
// (r14 champion leg, verbatim: ~41 us, at the mixed-leg fabric ceiling)
__global__ __launch_bounds__(256, 2) void qnn_p1(const float* __restrict__ in,
                                                 const float* __restrict__ theta,
                                                 float* __restrict__ out,
                                                 double* __restrict__ partials) {
    __shared__ __align__(16) float4 lds[4096];   // 64 KB
    __shared__ double red[4];
    const int t = threadIdx.x, lane = t & 63, w2 = t >> 6;
    const long gA = (long)blockIdx.x << 13;      // quad base, tile A
    const long gB = gA + 4096;                   // tile B

    float c0,s0,c1,s1,c2,s2,c3,s3,c4,s4,c5,s5,c6,s6;
    { float th;
      th=0.5f*theta[11]; c0=cosf(th); s0=sinf(th);
      th=0.5f*theta[10]; c1=cosf(th); s1=sinf(th);
      th=0.5f*theta[9];  c2=cosf(th); s2=sinf(th);
      th=0.5f*theta[8];  c3=cosf(th); s3=sinf(th);
      th=0.5f*theta[7];  c4=cosf(th); s4=sinf(th);
      th=0.5f*theta[6];  c5=cosf(th); s5=sinf(th);
      th=0.5f*theta[5];  c6=cosf(th); s6=sinf(th); }

    float4 f[16], g[16];
#pragma unroll
    for (int k = 0; k < 16; ++k)
        f[k] = nt_load4(in + ((gA + ((w2 << 10) | (k << 6) | lane)) << 2));
#pragma unroll
    for (int k = 0; k < 16; ++k)
        g[k] = nt_load4(in + ((gB + ((w2 << 10) | (k << 6) | lane)) << 2));

    const float sA = sumsq16(f);

#pragma unroll
    for (int k = 0; k < 16; ++k) {
        float ny = c0*f[k].y - s0*f[k].z;
        float nz = s0*f[k].y + c0*f[k].z;
        f[k].y = ny; f[k].z = nz;
    }
    rotshfl<16>(f, 0, c1, s1, lane);
    rotshfl<16>(f, 2, c2, s2, lane);
    rotshfl<16>(f, 4, c3, s3, lane);
#pragma unroll
    for (int hi = 0; hi < 16; hi += 4) rot4(f[hi+1], f[hi+2], c4, s4);
#pragma unroll
    for (int lo = 0; lo < 4; ++lo)     rot4(f[4+lo], f[8+lo], c5, s5);

#pragma unroll
    for (int k = 0; k < 16; ++k) lds[(w2 << 10) | (k << 6) | lane] = f[k];
    bar_lgkm();
#pragma unroll
    for (int m = 0; m < 16; ++m) f[m] = lds[(m << 8) | (w2 << 6) | lane];
#pragma unroll
    for (int lo = 0; lo < 4; ++lo) rot4(f[4+lo], f[8+lo], c6, s6);
#pragma unroll
    for (int m = 0; m < 16; ++m)
        *(float4*)(out + ((gA + ((m << 8) | (w2 << 6) | lane)) << 2)) = f[m];

    const float sB = sumsq16(g);
#pragma unroll
    for (int k = 0; k < 16; ++k) {
        float ny = c0*g[k].y - s0*g[k].z;
        float nz = s0*g[k].y + c0*g[k].z;
        g[k].y = ny; g[k].z = nz;
    }
    rotshfl<16>(g, 0, c1, s1, lane);
    rotshfl<16>(g, 2, c2, s2, lane);
    rotshfl<16>(g, 4, c3, s3, lane);
#pragma unroll
    for (int hi = 0; hi < 16; hi += 4) rot4(g[hi+1], g[hi+2], c4, s4);
#pragma unroll
    for (int lo = 0; lo < 4; ++lo)     rot4(g[4+lo], g[8+lo], c5, s5);

    bar_lgkm();
#pragma unroll
    for (int k = 0; k < 16; ++k) lds[(w2 << 10) | (k << 6) | lane] = g[k];
    bar_lgkm();
#pragma unroll
    for (int m = 0; m < 16; ++m) g[m] = lds[(m << 8) | (w2 << 6) | lane];
#pragma unroll
    for (int lo = 0; lo < 4; ++lo) rot4(g[4+lo], g[8+lo], c6, s6);
#pragma unroll
    for (int m = 0; m < 16; ++m)
        *(float4*)(out + ((gB + ((m << 8) | (w2 << 6) | lane)) << 2)) = g[m];

    double acc = (double)sA + (double)sB;
#pragma unroll
    for (int off = 32; off > 0; off >>= 1) acc += __shfl_down(acc, off, 64);
    if (lane == 0) red[w2] = acc;
    bar_lgkm();
    if (t == 0)
        partials[blockIdx.x] = red[0] + red[1] + red[2] + red[3];
}

// ---------------- Norm: 1024 partials -> scale = cos(theta[0]/2)/sqrt(sum) ---------
__global__ void qnn_norm(const double* __restrict__ partials,
                         const float* __restrict__ theta,
                         double* __restrict__ scale) {
    __shared__ double w[4];
    const int t = threadIdx.x;
    double acc = 0.0;
    for (int i = t; i < 1024; i += 256) acc += partials[i];
#pragma unroll
    for (int off = 32; off > 0; off >>= 1) acc += __shfl_down(acc, off, 64);
    if ((t & 63) == 0) w[t >> 6] = acc;
    __syncthreads();
    if (t == 0) {
        double tot = w[0] + w[1] + w[2] + w[3];
        *scale = (double)cosf(0.5f * theta[0]) / sqrt(tot);
    }
}

// ---------------- qnn_high: pairs j7..j11 (el bits 14..23) + scale, in place -------
// 512 B granules. Tile slot s (13 bits) = H<<5 | pq; H = el 14..21 (s 5..12),
// pq = el 2..6 (32 quads = 512 B contiguous).
// Global quad = b24<<22 | e23<<21 | e22<<20 | (s>>5)<<12 | mid<<5 | (s&31);
// grid bid = b24<<8 | p<<7 | mid (512 blocks). Parity tile-pairing for j11
// (el 23,22): p=0 -> tiles (00),(11) [identity]; p=1 -> (01),(10) [rot f x g].
// Load s = k<<9 | t: j9 = (s10,s9) = k(1,0); j10 = (s12,s11) = k(3,2).
// LDS exchange to s' = (t>>5)<<9 | m<<5 | (t&31): j7 = (s6,s5) = m(1,0);
// j8 = (s8,s7) = m(3,2). Zero lane shuffles. 32 upfront loads, 3 lgkm barriers.
// Regular loads (IC-resident intermediate), NT final stores.
__global__ __launch_bounds__(512, 2) void qnn_high(float* __restrict__ buf,
                                                   const float* __restrict__ theta,
                                                   const double* __restrict__ scale) {
    __shared__ __align__(16) float4 lds[8192];   // 128 KB
    const int t = threadIdx.x;
    const int bid = blockIdx.x;
    const int b24 = bid >> 8, p = (bid >> 7) & 1, mid = bid & 127;
    const long baseA = ((long)b24 << 22) | (p ? (1L << 20) : 0)        | ((long)mid << 5);
    const long baseB = ((long)b24 << 22) | (p ? (2L << 20) : (3L << 20)) | ((long)mid << 5);

    float c7,s7,c8,s8,c9,s9,c10,s10,c11,s11;
    { float th;
      th=0.5f*theta[4]; c7 =cosf(th); s7 =sinf(th);
      th=0.5f*theta[3]; c8 =cosf(th); s8 =sinf(th);
      th=0.5f*theta[2]; c9 =cosf(th); s9 =sinf(th);
      th=0.5f*theta[1]; c10=cosf(th); s10=sinf(th);
      th=0.5f*theta[0]; c11=cosf(th); s11=sinf(th); }
    const float sc = (float)(*scale);

    const int rb = ((t >> 5) << 9) | (t & 31);   // read base: hi = s 9..12, lo = s 0..4

    float4 f[16], g[16];
    // ---- issue ALL 32 loads (regular; 512 B granules) ----
#pragma unroll
    for (int k = 0; k < 16; ++k) {
        const int s_ = (k << 9) | t;
        f[k] = *(const float4*)(buf + ((baseA | ((long)(s_ >> 5) << 12) | (s_ & 31)) << 2));
    }
#pragma unroll
    for (int k = 0; k < 16; ++k) {
        const int s_ = (k << 9) | t;
        g[k] = *(const float4*)(buf + ((baseB | ((long)(s_ >> 5) << 12) | (s_ & 31)) << 2));
    }

    // ---- j11 cross-tile (odd blocks only; block-uniform branch) ----
    if (p) {
#pragma unroll
        for (int k = 0; k < 16; ++k) rot4(f[k], g[k], c11, s11);
    }
    // ---- j9 = k(1,0), j10 = k(3,2) ----
#pragma unroll
    for (int q = 0; q < 16; q += 4) {
        rot4(f[q+1], f[q+2], c9, s9);
        rot4(g[q+1], g[q+2], c9, s9);
    }
#pragma unroll
    for (int lo = 0; lo < 4; ++lo) {
        rot4(f[4+lo], f[8+lo], c10, s10);
        rot4(g[4+lo], g[8+lo], c10, s10);
    }

    // ---- tile A: LDS trip for j7/j8, scale, NT store ----
#pragma unroll
    for (int k = 0; k < 16; ++k) lds[(k << 9) | t] = f[k];
    bar_lgkm();
#pragma unroll
    for (int m = 0; m < 16; ++m) f[m] = lds[rb | (m << 5)];
#pragma unroll
    for (int q = 0; q < 16; q += 4) rot4(f[q+1], f[q+2], c7, s7);   // j7 = m(1,0)
#pragma unroll
    for (int lo = 0; lo < 4; ++lo)  rot4(f[4+lo], f[8+lo], c8, s8); // j8 = m(3,2)
#pragma unroll
    for (int m = 0; m < 16; ++m) {
        const int s_ = rb | (m << 5);
        float4 v = f[m];
        v.x *= sc; v.y *= sc; v.z *= sc; v.w *= sc;
        nt_store4(buf + ((baseA | ((long)(s_ >> 5) << 12) | (s_ & 31)) << 2), v);
    }
    bar_lgkm();   // all waves done reading A's LDS image

    // ---- tile B ----
#pragma unroll
    for (int k = 0; k < 16; ++k) lds[(k << 9) | t] = g[k];
    bar_lgkm();
#pragma unroll
    for (int m = 0; m < 16; ++m) g[m] = lds[rb | (m << 5)];
#pragma unroll
    for (int q = 0; q < 16; q += 4) rot4(g[q+1], g[q+2], c7, s7);
#pragma unroll
    for (int lo = 0; lo < 4; ++lo)  rot4(g[4+lo], g[8+lo], c8, s8);
#pragma unroll
    for (int m = 0; m < 16; ++m) {
        const int s_ = rb | (m << 5);
        float4 v = g[m];
        v.x *= sc; v.y *= sc; v.z *= sc; v.w *= sc;
        nt_store4(buf + ((baseB | ((long)(s_ >> 5) << 12) | (s_ & 31)) << 2), v);
    }
}

extern "C" void kernel_launch(void* const* d_in, const int* in_sizes, int n_in,
                              void* d_out, int out_size, void* d_ws, size_t ws_size,
                              hipStream_t stream) {
    const float* in = (const float*)d_in[0];      // feature, 2^25 f32
    const float* theta = (const float*)d_in[1];   // 13 f32
    float* out = (float*)d_out;                   // 2^25 f32
    double* part = (double*)d_ws;                 // 1024 partials + 1 scale
    double* scale = part + 1024;

    qnn_p1<<<1024, 256, 0, stream>>>(in, theta, out, part);
    qnn_norm<<<1, 256, 0, stream>>>(part, theta, scale);
    qnn_high<<<512, 512, 0, stream>>>(out, theta, scale);
}